// Round 15
// baseline (198.143 us; speedup 1.0000x reference)
//
#include <hip/hip_runtime.h>
#include <stdint.h>

#define Hdim 512
#define Bdim 128
#define Ldim 512
#define Vdim 2048

typedef unsigned short u16;
using f32x4  = float  __attribute__((ext_vector_type(4)));
using f32x8  = float  __attribute__((ext_vector_type(8)));
using bf16x8 = __bf16 __attribute__((ext_vector_type(8)));
using bf16x2 = __bf16 __attribute__((ext_vector_type(2)));

__device__ inline u16 f2bf(float x) {
  __bf16 b = (__bf16)x;
  union { __bf16 b; u16 u; } c; c.b = b; return c.u;
}
__device__ inline uint32_t pk2(float lo, float hi) {
  union { bf16x2 v; uint32_t u; } c;
  c.v[0] = (__bf16)lo; c.v[1] = (__bf16)hi;
  return c.u;
}
__device__ inline float fast_tanh(float x) {
  return 1.0f - 2.0f / (__expf(2.0f * x) + 1.0f);
}
__device__ inline float fast_sig(float x) { return 1.0f / (1.0f + __expf(-x)); }

__device__ inline bf16x8 pack_bf8(float4 x, float4 y) {
  f32x8 f = {x.x, x.y, x.z, x.w, y.x, y.y, y.z, y.w};
  return __builtin_convertvector(f, bf16x8);
}

// =======================================================================
// prep (unchanged from R14): qW GEMM | mask detect | weight arena etc.
// arena: Wenc@0 (512x512), Wcat@262144 (512x1024), Wg0p@786432 (2048x1536),
//        Wg1p@3932160 (2048x1024)  total 6029312 u16
// =======================================================================
__global__ __launch_bounds__(512)
void prep_kernel(const float* __restrict__ lh, const float* __restrict__ attn_W,
                 const float* __restrict__ attn_b, const float* __restrict__ cat_W,
                 const float* __restrict__ W_ih0, const float* __restrict__ W_hh0,
                 const float* __restrict__ W_ih1, const float* __restrict__ W_hh1,
                 const float* __restrict__ b_ih0, const float* __restrict__ b_hh0,
                 const float* __restrict__ b_ih1, const float* __restrict__ b_hh1,
                 const float* __restrict__ wdv, const int* __restrict__ ids,
                 const void* __restrict__ mask,
                 float* __restrict__ qW, u16* __restrict__ arena,
                 float* __restrict__ biasg0, float* __restrict__ biasg1,
                 u16* __restrict__ X0bf, u16* __restrict__ X1bf, int* __restrict__ flag) {
  int blk = blockIdx.x, t = threadIdx.x;
  int lane = t & 63, wid = t >> 6;
  int fr = lane & 15, g = lane >> 4, kof = g * 8;

  if (blk < 16) {
    int mh = wid & 3, nh = wid >> 2;
    int n0 = blk * 32 + nh * 16;
    int rb0 = mh * 32;
    f32x4 ac0 = {0.f, 0.f, 0.f, 0.f}, ac1 = {0.f, 0.f, 0.f, 0.f};
    const float* q = lh + 65536;
#pragma unroll 2
    for (int kt = 0; kt < 512; kt += 32) {
      const float* qr0 = q + (size_t)(rb0 + fr) * 512 + kt + kof;
      const float* qr1 = qr0 + 16 * 512;
      const float* wr  = attn_W + (size_t)(n0 + fr) * 1024 + kt + kof;
      float4 x0 = *(const float4*)qr0, x1 = *(const float4*)(qr0 + 4);
      float4 y0 = *(const float4*)qr1, y1 = *(const float4*)(qr1 + 4);
      float4 w0 = *(const float4*)wr,  w1 = *(const float4*)(wr + 4);
      bf16x8 A0 = pack_bf8(x0, x1), A1 = pack_bf8(y0, y1), Bb = pack_bf8(w0, w1);
      ac0 = __builtin_amdgcn_mfma_f32_16x16x32_bf16(A0, Bb, ac0, 0, 0, 0);
      ac1 = __builtin_amdgcn_mfma_f32_16x16x32_bf16(A1, Bb, ac1, 0, 0, 0);
    }
    float vb = attn_b[n0 + fr];
#pragma unroll
    for (int j = 0; j < 4; ++j) {
      qW[(size_t)(rb0 + g * 4 + j) * 512 + n0 + fr]      = ac0[j] + vb;
      qW[(size_t)(rb0 + 16 + g * 4 + j) * 512 + n0 + fr] = ac1[j] + vb;
    }
    return;
  }
  if (blk == 16) {
    __shared__ int sf;
    if (t == 0) sf = 0;
    __syncthreads();
    const uint32_t* m32 = (const uint32_t*)mask;
    int found = 0;
    for (int i = t; i < 16384; i += 512)
      if (m32[i] & 0xffffff00u) found = 1;
    if (found) sf = 1;
    __syncthreads();
    if (t == 0) *flag = sf;
    return;
  }
  const int ARENA_Q = 1507328;
  int i = (blk - 17) * 512 + t;
  if (i < ARENA_Q) {
    int e = i * 4;
    float4 v = {0.f, 0.f, 0.f, 0.f};
    if (e < 262144) {
      int o = e >> 9, k = e & 511;
      v = *(const float4*)(attn_W + (size_t)o * 1024 + 512 + k);
    } else if (e < 786432) {
      int e2 = e - 262144; int o = e2 >> 10, k = e2 & 1023;
      v = *(const float4*)(cat_W + (size_t)o * 1024 + k);
    } else if (e < 3932160) {
      int e2 = e - 786432; int row = e2 / 1536, k = e2 % 1536;
      int o = row >> 2, gt = row & 3;
      if (gt == 0)      v = (k < 1024) ? *(const float4*)(W_ih0 + (size_t)o * 1024 + k)
                                       : *(const float4*)(W_hh0 + (size_t)o * 512 + k - 1024);
      else if (gt == 1) v = (k < 1024) ? *(const float4*)(W_ih0 + (size_t)(512 + o) * 1024 + k)
                                       : *(const float4*)(W_hh0 + (size_t)(512 + o) * 512 + k - 1024);
      else if (gt == 2) { if (k < 1024)  v = *(const float4*)(W_ih0 + (size_t)(1024 + o) * 1024 + k); }
      else              { if (k >= 1024) v = *(const float4*)(W_hh0 + (size_t)(1024 + o) * 512 + k - 1024); }
    } else {
      int e2 = e - 3932160; int row = e2 >> 10, k = e2 & 1023;
      int o = row >> 2, gt = row & 3;
      if (gt == 0)      v = (k < 512) ? *(const float4*)(W_ih1 + (size_t)o * 512 + k)
                                      : *(const float4*)(W_hh1 + (size_t)o * 512 + k - 512);
      else if (gt == 1) v = (k < 512) ? *(const float4*)(W_ih1 + (size_t)(512 + o) * 512 + k)
                                      : *(const float4*)(W_hh1 + (size_t)(512 + o) * 512 + k - 512);
      else if (gt == 2) { if (k < 512)  v = *(const float4*)(W_ih1 + (size_t)(1024 + o) * 512 + k); }
      else              { if (k >= 512) v = *(const float4*)(W_hh1 + (size_t)(1024 + o) * 512 + k - 512); }
    }
    ushort4 u;
    u.x = f2bf(v.x); u.y = f2bf(v.y); u.z = f2bf(v.z); u.w = f2bf(v.w);
    *(ushort4*)(arena + e) = u;
    return;
  }
  int i2 = i - ARENA_Q;
  if (i2 < 1024) {
    int r4 = i2 * 4; int layer = r4 >> 11; int r = r4 & 2047; int o = r >> 2;
    const float* bi = layer ? b_ih1 : b_ih0;
    const float* bh = layer ? b_hh1 : b_hh0;
    float4 v;
    v.x = bi[o] + bh[o];
    v.y = bi[512 + o] + bh[512 + o];
    v.z = bi[1024 + o];
    v.w = bh[1024 + o];
    *(float4*)((layer ? biasg1 : biasg0) + r) = v;
  } else if (i2 < 1024 + 16384) {
    int j = (i2 - 1024) * 4; int b = j >> 9, i0 = j & 511;
    float4 v = *(const float4*)(wdv + (size_t)b * (Vdim * Hdim) + (size_t)ids[b] * 512 + i0);
    ushort4 u;
    u.x = f2bf(v.x); u.y = f2bf(v.y); u.z = f2bf(v.z); u.w = f2bf(v.w);
    *(ushort4*)(X0bf + b * 1536 + i0) = u;
  } else if (i2 < 1024 + 32768) {
    int j = (i2 - 1024 - 16384) * 4; int b = j >> 9, i0 = j & 511;
    float4 v = *(const float4*)(lh + (size_t)b * 512 + i0);
    ushort4 u;
    u.x = f2bf(v.x); u.y = f2bf(v.y); u.z = f2bf(v.z); u.w = f2bf(v.w);
    *(ushort4*)(X0bf + b * 1536 + 1024 + i0) = u;
  } else if (i2 < 1024 + 49152) {
    int j = (i2 - 1024 - 32768) * 4; int b = j >> 9, i0 = j & 511;
    float4 v = *(const float4*)(lh + 65536 + (size_t)b * 512 + i0);
    ushort4 u;
    u.x = f2bf(v.x); u.y = f2bf(v.y); u.z = f2bf(v.z); u.w = f2bf(v.w);
    *(ushort4*)(X1bf + b * 1024 + 512 + i0) = u;
  }
}

// =======================================================================
// attn_fused: grid 512 = (b = blk>>2, lc = blk&3). Per block: energy GEMM
// (128 l x 512 o, o in two sequential 256-halves, fixed b), mask + local
// softmax over the chunk's 128 l's, ctx_partial[512] = sum_l e_l*enc[l,b,:]
// (rows L2-hot). Writes ctx_partial + (m_local, s_local).
// =======================================================================
__global__ __launch_bounds__(512)
void attn_fused_kernel(const float* __restrict__ enc, const u16* __restrict__ Wenc,
                       const float* __restrict__ qW, const float* __restrict__ scW,
                       const void* __restrict__ maskp, const int* __restrict__ flag,
                       float* __restrict__ ctxp, float* __restrict__ ms) {
  __shared__ __align__(16) u16 As[2][128 * 40];
  __shared__ float part[8 * 128];
  __shared__ float score[128];
  __shared__ float redx[8];
  int blk = blockIdx.x, t = threadIdx.x;
  int lane = t & 63, wid = t >> 6;
  int fr = lane & 15, g = lane >> 4, kof = g * 8;
  int b = blk >> 2, lc = blk & 3;
  const int arow = t >> 2;             // 0..127 = l-local
  const int aks = (t & 3) * 8;

  if (t < 128) score[t] = 0.f;

  const float* abase = enc + (((size_t)(lc * 128 + arow)) * 128 + b) * 512 + aks;

  for (int oh = 0; oh < 2; ++oh) {
    int ob = oh * 256;
    f32x4 acc[8][2];
#pragma unroll
    for (int i = 0; i < 8; ++i) {
      acc[i][0] = (f32x4){0.f, 0.f, 0.f, 0.f};
      acc[i][1] = (f32x4){0.f, 0.f, 0.f, 0.f};
    }
    const u16* bptr0 = Wenc + (size_t)(ob + wid * 32 + fr) * 512 + kof;
    const u16* bptr1 = bptr0 + (size_t)16 * 512;
    float4 pA0 = *(const float4*)abase;
    float4 pA1 = *(const float4*)(abase + 4);
    float4 pB0 = *(const float4*)(abase + 32);
    float4 pB1 = *(const float4*)(abase + 36);
    bf16x8 cb0 = *(const bf16x8*)bptr0;
    bf16x8 cb1 = *(const bf16x8*)bptr1;

#pragma unroll 2
    for (int step = 0; step < 16; ++step) {
      int sel = step & 1;
      __syncthreads();
      bf16x8 apv = pack_bf8(pA0, pA1);
      *(bf16x8*)(&As[sel][arow * 40 + aks]) = apv;
      pA0 = pB0; pA1 = pB1;
      if (step < 14) {
        int kt = (step + 2) * 32;
        pB0 = *(const float4*)(abase + kt);
        pB1 = *(const float4*)(abase + kt + 4);
      }
      bf16x8 nb0 = cb0, nb1 = cb1;
      if (step < 15) {
        int kt = (step + 1) * 32;
        nb0 = *(const bf16x8*)(bptr0 + kt);
        nb1 = *(const bf16x8*)(bptr1 + kt);
      }
      __syncthreads();
#pragma unroll
      for (int mi = 0; mi < 8; ++mi) {
        bf16x8 av = *(const bf16x8*)(&As[sel][(mi * 16 + fr) * 40 + kof]);
        acc[mi][0] = __builtin_amdgcn_mfma_f32_16x16x32_bf16(av, cb0, acc[mi][0], 0, 0, 0);
        acc[mi][1] = __builtin_amdgcn_mfma_f32_16x16x32_bf16(av, cb1, acc[mi][1], 0, 0, 0);
      }
      cb0 = nb0; cb1 = nb1;
    }
    // epilogue: b fixed -> qW/scW are 2 scalars per lane
    float sw0 = scW[ob + wid * 32 + fr];
    float sw1 = scW[ob + wid * 32 + 16 + fr];
    float q0  = qW[(size_t)b * 512 + ob + wid * 32 + fr];
    float q1  = qW[(size_t)b * 512 + ob + wid * 32 + 16 + fr];
#pragma unroll
    for (int mi = 0; mi < 8; ++mi) {
      float rs0 = sw0 * fast_tanh(acc[mi][0][0] + q0) + sw1 * fast_tanh(acc[mi][1][0] + q1);
      float rs1 = sw0 * fast_tanh(acc[mi][0][1] + q0) + sw1 * fast_tanh(acc[mi][1][1] + q1);
      float rs2 = sw0 * fast_tanh(acc[mi][0][2] + q0) + sw1 * fast_tanh(acc[mi][1][2] + q1);
      float rs3 = sw0 * fast_tanh(acc[mi][0][3] + q0) + sw1 * fast_tanh(acc[mi][1][3] + q1);
#pragma unroll
      for (int d = 1; d < 16; d <<= 1) {
        rs0 += __shfl_xor(rs0, d);
        rs1 += __shfl_xor(rs1, d);
        rs2 += __shfl_xor(rs2, d);
        rs3 += __shfl_xor(rs3, d);
      }
      if (fr < 4) {
        float v = (fr == 0) ? rs0 : (fr == 1) ? rs1 : (fr == 2) ? rs2 : rs3;
        part[wid * 128 + mi * 16 + g * 4 + fr] = v;
      }
    }
    __syncthreads();
    if (t < 128) {
      float s = 0.f;
#pragma unroll
      for (int w2 = 0; w2 < 8; ++w2) s += part[w2 * 128 + t];
      score[t] += s;
    }
    __syncthreads();
  }

  // ---- phase 2: mask + local softmax + ctx partial ----
  bool isbyte = (*flag != 0);
  if (t < 128) {
    int l = lc * 128 + t;
    bool m = isbyte ? (((const uint8_t*)maskp)[b * 512 + l] != 0)
                    : (((const int*)maskp)[b * 512 + l] != 0);
    if (m) score[t] = -1e12f;
  }
  __syncthreads();
  // local max over 128 (all threads participate; t>=128 contribute -inf)
  float v = (t < 128) ? score[t] : -1e12f;
#pragma unroll
  for (int d = 1; d < 64; d <<= 1) v = fmaxf(v, __shfl_xor(v, d));
  if (lane == 0) redx[wid] = v;
  __syncthreads();
  float mloc = redx[0];
#pragma unroll
  for (int w2 = 1; w2 < 8; ++w2) mloc = fmaxf(mloc, redx[w2]);
  // exp + local sum (weights left unnormalized; finalize divides)
  float e = 0.f;
  if (t < 128) {
    e = __expf(score[t] - mloc);
  }
  __syncthreads();
  if (t < 128) score[t] = e;
#pragma unroll
  for (int d = 1; d < 64; d <<= 1) e += __shfl_xor(e, d);
  if (lane == 0) redx[wid] = e;
  __syncthreads();
  float sloc = redx[0] + redx[1] + redx[2] + redx[3] +
               redx[4] + redx[5] + redx[6] + redx[7];
  // ctx partial: thread t owns column h=t; rows are L2-hot from the GEMM
  float a = 0.f;
  const float* eb = enc + (((size_t)(lc * 128)) * 128 + b) * 512 + t;
#pragma unroll 4
  for (int i = 0; i < 128; ++i)
    a += score[i] * eb[(size_t)i * 65536];
  ctxp[((size_t)b * 4 + lc) * 512 + t] = a;
  if (t == 0) {
    ms[(b * 4 + lc) * 2 + 0] = mloc;
    ms[(b * 4 + lc) * 2 + 1] = sloc;
  }
}

// =======================================================================
// finalize: combine 4 chunk partials per b -> ctx, write X0bf/c1bf bf16.
// grid 128, block 512 (thread = h).
// =======================================================================
__global__ __launch_bounds__(512)
void finalize_kernel(const float* __restrict__ ctxp, const float* __restrict__ ms,
                     u16* __restrict__ X0bf, u16* __restrict__ c1bf) {
  int b = blockIdx.x, t = threadIdx.x;
  float m0 = ms[b * 8 + 0], s0 = ms[b * 8 + 1];
  float m1 = ms[b * 8 + 2], s1 = ms[b * 8 + 3];
  float m2 = ms[b * 8 + 4], s2 = ms[b * 8 + 5];
  float m3 = ms[b * 8 + 6], s3 = ms[b * 8 + 7];
  float M = fmaxf(fmaxf(m0, m1), fmaxf(m2, m3));
  float e0 = __expf(m0 - M), e1 = __expf(m1 - M);
  float e2 = __expf(m2 - M), e3 = __expf(m3 - M);
  float S = s0 * e0 + s1 * e1 + s2 * e2 + s3 * e3;
  float a = ctxp[((size_t)b * 4 + 0) * 512 + t] * e0
          + ctxp[((size_t)b * 4 + 1) * 512 + t] * e1
          + ctxp[((size_t)b * 4 + 2) * 512 + t] * e2
          + ctxp[((size_t)b * 4 + 3) * 512 + t] * e3;
  u16 cv = f2bf(a / S);
  X0bf[b * 1536 + 512 + t] = cv;
  c1bf[b * 1024 + 512 + t] = cv;
}

// =======================================================================
// GRU layer: GEMM (gate-interleaved W: row 4o+g) + fused combine epilogue.
// =======================================================================
__global__ __launch_bounds__(256)
void gru_gemm_kernel(const u16* __restrict__ X, int ldx, const u16* __restrict__ Wp,
                     const float* __restrict__ biasp, const float* __restrict__ hprev,
                     int K, float* __restrict__ hout, u16* __restrict__ xdst) {
  __shared__ float ct[128][36];
  int n0 = blockIdx.x * 32;
  int t = threadIdx.x, lane = t & 63, w = t >> 6;
  int fr = lane & 15, g = lane >> 4, kof = g * 8;
  f32x4 acc[2][2];
#pragma unroll
  for (int i = 0; i < 2; ++i)
#pragma unroll
    for (int j = 0; j < 2; ++j) acc[i][j] = (f32x4){0.f, 0.f, 0.f, 0.f};
  const u16* Xr0 = X + (size_t)(w * 32 + fr) * ldx;
  const u16* Xr1 = Xr0 + (size_t)16 * ldx;
  const u16* Wr0 = Wp + (size_t)(n0 + fr) * K;
  const u16* Wr1 = Wp + (size_t)(n0 + 16 + fr) * K;
#pragma unroll 4
  for (int kt = 0; kt < K; kt += 32) {
    bf16x8 a0 = *(const bf16x8*)(Xr0 + kt + kof);
    bf16x8 a1 = *(const bf16x8*)(Xr1 + kt + kof);
    bf16x8 b0 = *(const bf16x8*)(Wr0 + kt + kof);
    bf16x8 b1 = *(const bf16x8*)(Wr1 + kt + kof);
    acc[0][0] = __builtin_amdgcn_mfma_f32_16x16x32_bf16(a0, b0, acc[0][0], 0, 0, 0);
    acc[0][1] = __builtin_amdgcn_mfma_f32_16x16x32_bf16(a0, b1, acc[0][1], 0, 0, 0);
    acc[1][0] = __builtin_amdgcn_mfma_f32_16x16x32_bf16(a1, b0, acc[1][0], 0, 0, 0);
    acc[1][1] = __builtin_amdgcn_mfma_f32_16x16x32_bf16(a1, b1, acc[1][1], 0, 0, 0);
  }
#pragma unroll
  for (int mi = 0; mi < 2; ++mi)
#pragma unroll
    for (int ni = 0; ni < 2; ++ni) {
      int col = ni * 16 + fr;
      float vb = biasp[n0 + col];
#pragma unroll
      for (int j = 0; j < 4; ++j)
        ct[w * 32 + 16 * mi + g * 4 + j][col] = acc[mi][ni][j] + vb;
    }
  __syncthreads();
#pragma unroll
  for (int i = 0; i < 4; ++i) {
    int u = t + i * 256;
    int b = u >> 3, ol = u & 7;
    float cr  = ct[b][ol * 4 + 0];
    float cz  = ct[b][ol * 4 + 1];
    float ci  = ct[b][ol * 4 + 2];
    float chh = ct[b][ol * 4 + 3];
    int o = blockIdx.x * 8 + ol;
    float r = fast_sig(cr), z = fast_sig(cz);
    float n = tanhf(ci + r * chh);
    float h = (1.0f - z) * n + z * hprev[b * 512 + o];
    hout[b * 512 + o] = h;
    xdst[b * 1024 + o] = f2bf(h);
  }
}

// =======================================================================
// thin GEMM, N-tile 32: C = act(X @ W^T + bias). grid N/32, block 256.
// =======================================================================
__global__ __launch_bounds__(256)
void thin_gemm32(const u16* __restrict__ X, int ldx, const u16* __restrict__ W,
                 const float* __restrict__ bias, float* __restrict__ C, int ldc,
                 int K, int act) {
  int n0 = blockIdx.x * 32;
  int t = threadIdx.x, lane = t & 63, w = t >> 6;
  int fr = lane & 15, g = lane >> 4, kof = g * 8;
  f32x4 acc[2][2];
#pragma unroll
  for (int i = 0; i < 2; ++i)
#pragma unroll
    for (int j = 0; j < 2; ++j) acc[i][j] = (f32x4){0.f, 0.f, 0.f, 0.f};
  const u16* Xr0 = X + (size_t)(w * 32 + fr) * ldx;
  const u16* Xr1 = Xr0 + (size_t)16 * ldx;
  const u16* Wr0 = W + (size_t)(n0 + fr) * K;
  const u16* Wr1 = W + (size_t)(n0 + 16 + fr) * K;
#pragma unroll 4
  for (int kt = 0; kt < K; kt += 32) {
    bf16x8 a0 = *(const bf16x8*)(Xr0 + kt + kof);
    bf16x8 a1 = *(const bf16x8*)(Xr1 + kt + kof);
    bf16x8 b0 = *(const bf16x8*)(Wr0 + kt + kof);
    bf16x8 b1 = *(const bf16x8*)(Wr1 + kt + kof);
    acc[0][0] = __builtin_amdgcn_mfma_f32_16x16x32_bf16(a0, b0, acc[0][0], 0, 0, 0);
    acc[0][1] = __builtin_amdgcn_mfma_f32_16x16x32_bf16(a0, b1, acc[0][1], 0, 0, 0);
    acc[1][0] = __builtin_amdgcn_mfma_f32_16x16x32_bf16(a1, b0, acc[1][0], 0, 0, 0);
    acc[1][1] = __builtin_amdgcn_mfma_f32_16x16x32_bf16(a1, b1, acc[1][1], 0, 0, 0);
  }
#pragma unroll
  for (int mi = 0; mi < 2; ++mi)
#pragma unroll
    for (int ni = 0; ni < 2; ++ni) {
      int col = n0 + ni * 16 + fr;
      float vb = bias[col];
#pragma unroll
      for (int j = 0; j < 4; ++j) {
        int row = w * 32 + 16 * mi + g * 4 + j;
        float v = acc[mi][ni][j] + vb;
        if (act) v = tanhf(v);
        C[(size_t)row * ldc + col] = v;
      }
    }
}

extern "C" void kernel_launch(void* const* d_in, const int* in_sizes, int n_in,
                              void* d_out, int out_size, void* d_ws, size_t ws_size,
                              hipStream_t stream) {
  const int*   ids    = (const int*)  d_in[0];
  const float* lh     = (const float*)d_in[1];
  const float* wdv    = (const float*)d_in[2];
  const float* enc    = (const float*)d_in[3];
  const void*  mask   = d_in[4];
  const float* attn_W = (const float*)d_in[5];
  const float* attn_b = (const float*)d_in[6];
  const float* scW    = (const float*)d_in[7];
  const float* cat_W  = (const float*)d_in[8];
  const float* cat_b  = (const float*)d_in[9];
  const float* W_ih0  = (const float*)d_in[10];
  const float* W_hh0  = (const float*)d_in[11];
  const float* b_ih0  = (const float*)d_in[12];
  const float* b_hh0  = (const float*)d_in[13];
  const float* W_ih1  = (const float*)d_in[14];
  const float* W_hh1  = (const float*)d_in[15];
  const float* b_ih1  = (const float*)d_in[16];
  const float* b_hh1  = (const float*)d_in[17];

  float* out = (float*)d_out;
  float* h0  = out + 65536;
  float* h1  = out + 131072;

  float* ws     = (float*)d_ws;
  float* qW     = ws;                      // 65536
  float* ctxp   = ws + 65536;              // 262144 [128][4][512]
  float* ms     = ws + 327680;             // 1024   [128][4][2]
  float* biasg0 = ws + 328704;             // 2048
  float* biasg1 = ws + 330752;             // 2048
  int*   flag   = (int*)(ws + 332800);     // 16
  u16*   arena  = (u16*)(ws + 332816);     // 6029312 u16
  u16*   X0bf   = (u16*)(ws + 3347472);    // 196608 u16
  u16*   X1bf   = (u16*)(ws + 3445776);    // 131072 u16
  u16*   c1bf   = (u16*)(ws + 3511312);    // 131072 u16

  const u16* Wenc = arena;
  const u16* Wcat = arena + 262144;
  const u16* Wg0p = arena + 786432;
  const u16* Wg1p = arena + 3932160;

  prep_kernel<<<3059, 512, 0, stream>>>(lh, attn_W, attn_b, cat_W,
                                        W_ih0, W_hh0, W_ih1, W_hh1,
                                        b_ih0, b_hh0, b_ih1, b_hh1,
                                        wdv, ids, mask,
                                        qW, arena, biasg0, biasg1, X0bf, X1bf, flag);
  attn_fused_kernel<<<512, 512, 0, stream>>>(enc, Wenc, qW, scW, mask, flag, ctxp, ms);
  finalize_kernel<<<128, 512, 0, stream>>>(ctxp, ms, X0bf, c1bf);
  gru_gemm_kernel<<<64, 256, 0, stream>>>(X0bf, 1536, Wg0p, biasg0, lh, 1536, h0, X1bf);
  gru_gemm_kernel<<<64, 256, 0, stream>>>(X1bf, 1024, Wg1p, biasg1, lh + 65536, 1024, h1, c1bf);
  thin_gemm32<<<16, 256, 0, stream>>>(c1bf, 1024, Wcat, cat_b, out, 512, 1024, 1);
}

// Round 16
// 196.088 us; speedup vs baseline: 1.0105x; 1.0105x over previous
//
#include <hip/hip_runtime.h>
#include <stdint.h>

#define Hdim 512
#define Bdim 128
#define Ldim 512
#define Vdim 2048

typedef unsigned short u16;
using f32x4  = float  __attribute__((ext_vector_type(4)));
using f32x8  = float  __attribute__((ext_vector_type(8)));
using bf16x8 = __bf16 __attribute__((ext_vector_type(8)));
using bf16x2 = __bf16 __attribute__((ext_vector_type(2)));
using bf16x4 = __bf16 __attribute__((ext_vector_type(4)));

__device__ inline u16 f2bf(float x) {
  __bf16 b = (__bf16)x;
  union { __bf16 b; u16 u; } c; c.b = b; return c.u;
}
__device__ inline uint32_t pk2(float lo, float hi) {
  union { bf16x2 v; uint32_t u; } c;
  c.v[0] = (__bf16)lo; c.v[1] = (__bf16)hi;
  return c.u;
}
__device__ inline float fast_tanh(float x) {
  return 1.0f - 2.0f / (__expf(2.0f * x) + 1.0f);
}
__device__ inline float fast_sig(float x) { return 1.0f / (1.0f + __expf(-x)); }

__device__ inline bf16x8 pack_bf8(float4 x, float4 y) {
  f32x8 f = {x.x, x.y, x.z, x.w, y.x, y.y, y.z, y.w};
  return __builtin_convertvector(f, bf16x8);
}

// =======================================================================
// prep: blk<16 -> qW GEMM; blk==16 -> mask detect; blk>=17 -> weight arena
// + fused biases + emb gather + lh copies. (R14-proven)
// arena: Wenc@0 (512x512), Wcat@262144 (512x1024), Wg0p@786432 (2048x1536),
//        Wg1p@3932160 (2048x1024)  total 6029312 u16
// =======================================================================
__global__ __launch_bounds__(512)
void prep_kernel(const float* __restrict__ lh, const float* __restrict__ attn_W,
                 const float* __restrict__ attn_b, const float* __restrict__ cat_W,
                 const float* __restrict__ W_ih0, const float* __restrict__ W_hh0,
                 const float* __restrict__ W_ih1, const float* __restrict__ W_hh1,
                 const float* __restrict__ b_ih0, const float* __restrict__ b_hh0,
                 const float* __restrict__ b_ih1, const float* __restrict__ b_hh1,
                 const float* __restrict__ wdv, const int* __restrict__ ids,
                 const void* __restrict__ mask,
                 float* __restrict__ qW, u16* __restrict__ arena,
                 float* __restrict__ biasg0, float* __restrict__ biasg1,
                 u16* __restrict__ X0bf, u16* __restrict__ X1bf, int* __restrict__ flag) {
  int blk = blockIdx.x, t = threadIdx.x;
  int lane = t & 63, wid = t >> 6;
  int fr = lane & 15, g = lane >> 4, kof = g * 8;

  if (blk < 16) {
    int mh = wid & 3, nh = wid >> 2;
    int n0 = blk * 32 + nh * 16;
    int rb0 = mh * 32;
    f32x4 ac0 = {0.f, 0.f, 0.f, 0.f}, ac1 = {0.f, 0.f, 0.f, 0.f};
    const float* q = lh + 65536;
#pragma unroll 2
    for (int kt = 0; kt < 512; kt += 32) {
      const float* qr0 = q + (size_t)(rb0 + fr) * 512 + kt + kof;
      const float* qr1 = qr0 + 16 * 512;
      const float* wr  = attn_W + (size_t)(n0 + fr) * 1024 + kt + kof;
      float4 x0 = *(const float4*)qr0, x1 = *(const float4*)(qr0 + 4);
      float4 y0 = *(const float4*)qr1, y1 = *(const float4*)(qr1 + 4);
      float4 w0 = *(const float4*)wr,  w1 = *(const float4*)(wr + 4);
      bf16x8 A0 = pack_bf8(x0, x1), A1 = pack_bf8(y0, y1), Bb = pack_bf8(w0, w1);
      ac0 = __builtin_amdgcn_mfma_f32_16x16x32_bf16(A0, Bb, ac0, 0, 0, 0);
      ac1 = __builtin_amdgcn_mfma_f32_16x16x32_bf16(A1, Bb, ac1, 0, 0, 0);
    }
    float vb = attn_b[n0 + fr];
#pragma unroll
    for (int j = 0; j < 4; ++j) {
      qW[(size_t)(rb0 + g * 4 + j) * 512 + n0 + fr]      = ac0[j] + vb;
      qW[(size_t)(rb0 + 16 + g * 4 + j) * 512 + n0 + fr] = ac1[j] + vb;
    }
    return;
  }
  if (blk == 16) {
    __shared__ int sf;
    if (t == 0) sf = 0;
    __syncthreads();
    const uint32_t* m32 = (const uint32_t*)mask;
    int found = 0;
    for (int i = t; i < 16384; i += 512)
      if (m32[i] & 0xffffff00u) found = 1;
    if (found) sf = 1;
    __syncthreads();
    if (t == 0) *flag = sf;
    return;
  }
  const int ARENA_Q = 1507328;
  int i = (blk - 17) * 512 + t;
  if (i < ARENA_Q) {
    int e = i * 4;
    float4 v = {0.f, 0.f, 0.f, 0.f};
    if (e < 262144) {
      int o = e >> 9, k = e & 511;
      v = *(const float4*)(attn_W + (size_t)o * 1024 + 512 + k);
    } else if (e < 786432) {
      int e2 = e - 262144; int o = e2 >> 10, k = e2 & 1023;
      v = *(const float4*)(cat_W + (size_t)o * 1024 + k);
    } else if (e < 3932160) {
      int e2 = e - 786432; int row = e2 / 1536, k = e2 % 1536;
      int o = row >> 2, gt = row & 3;
      if (gt == 0)      v = (k < 1024) ? *(const float4*)(W_ih0 + (size_t)o * 1024 + k)
                                       : *(const float4*)(W_hh0 + (size_t)o * 512 + k - 1024);
      else if (gt == 1) v = (k < 1024) ? *(const float4*)(W_ih0 + (size_t)(512 + o) * 1024 + k)
                                       : *(const float4*)(W_hh0 + (size_t)(512 + o) * 512 + k - 1024);
      else if (gt == 2) { if (k < 1024)  v = *(const float4*)(W_ih0 + (size_t)(1024 + o) * 1024 + k); }
      else              { if (k >= 1024) v = *(const float4*)(W_hh0 + (size_t)(1024 + o) * 512 + k - 1024); }
    } else {
      int e2 = e - 3932160; int row = e2 >> 10, k = e2 & 1023;
      int o = row >> 2, gt = row & 3;
      if (gt == 0)      v = (k < 512) ? *(const float4*)(W_ih1 + (size_t)o * 512 + k)
                                      : *(const float4*)(W_hh1 + (size_t)o * 512 + k - 512);
      else if (gt == 1) v = (k < 512) ? *(const float4*)(W_ih1 + (size_t)(512 + o) * 512 + k)
                                      : *(const float4*)(W_hh1 + (size_t)(512 + o) * 512 + k - 512);
      else if (gt == 2) { if (k < 512)  v = *(const float4*)(W_ih1 + (size_t)(1024 + o) * 512 + k); }
      else              { if (k >= 512) v = *(const float4*)(W_hh1 + (size_t)(1024 + o) * 512 + k - 512); }
    }
    ushort4 u;
    u.x = f2bf(v.x); u.y = f2bf(v.y); u.z = f2bf(v.z); u.w = f2bf(v.w);
    *(ushort4*)(arena + e) = u;
    return;
  }
  int i2 = i - ARENA_Q;
  if (i2 < 1024) {
    int r4 = i2 * 4; int layer = r4 >> 11; int r = r4 & 2047; int o = r >> 2;
    const float* bi = layer ? b_ih1 : b_ih0;
    const float* bh = layer ? b_hh1 : b_hh0;
    float4 v;
    v.x = bi[o] + bh[o];
    v.y = bi[512 + o] + bh[512 + o];
    v.z = bi[1024 + o];
    v.w = bh[1024 + o];
    *(float4*)((layer ? biasg1 : biasg0) + r) = v;
  } else if (i2 < 1024 + 16384) {
    int j = (i2 - 1024) * 4; int b = j >> 9, i0 = j & 511;
    float4 v = *(const float4*)(wdv + (size_t)b * (Vdim * Hdim) + (size_t)ids[b] * 512 + i0);
    ushort4 u;
    u.x = f2bf(v.x); u.y = f2bf(v.y); u.z = f2bf(v.z); u.w = f2bf(v.w);
    *(ushort4*)(X0bf + b * 1536 + i0) = u;
  } else if (i2 < 1024 + 32768) {
    int j = (i2 - 1024 - 16384) * 4; int b = j >> 9, i0 = j & 511;
    float4 v = *(const float4*)(lh + (size_t)b * 512 + i0);
    ushort4 u;
    u.x = f2bf(v.x); u.y = f2bf(v.y); u.z = f2bf(v.z); u.w = f2bf(v.w);
    *(ushort4*)(X0bf + b * 1536 + 1024 + i0) = u;
  } else if (i2 < 1024 + 49152) {
    int j = (i2 - 1024 - 32768) * 4; int b = j >> 9, i0 = j & 511;
    float4 v = *(const float4*)(lh + 65536 + (size_t)b * 512 + i0);
    ushort4 u;
    u.x = f2bf(v.x); u.y = f2bf(v.y); u.z = f2bf(v.z); u.w = f2bf(v.w);
    *(ushort4*)(X1bf + b * 1024 + 512 + i0) = u;
  }
}

// =======================================================================
// attention energies v3: ONE block per l (grid 512), 1024 threads = 16
// waves (2 M-halves x 8 O-64-groups). A (enc, l-major contiguous 256 KB)
// read from HBM exactly ONCE; B = full Wenc, global->reg (L2-resident,
// total 268 MB = same as R10). acc[4][4] = 64 VGPR; waves_per_eu(4,4)
// pins the 128-VGPR budget (16 waves/CU). Scores written COMPLETE.
// =======================================================================
__global__ __launch_bounds__(1024)
__attribute__((amdgpu_waves_per_eu(4, 4)))
void attn_kernel(const float* __restrict__ enc, const u16* __restrict__ Wenc,
                 const float* __restrict__ qW, const float* __restrict__ scW,
                 float* __restrict__ scores) {
  __shared__ __align__(16) u16 As[2][128 * 40];
  __shared__ float part[16 * 64];
  int l = blockIdx.x, t = threadIdx.x;
  int lane = t & 63, wid = t >> 6;          // 0..15
  int fr = lane & 15, g = lane >> 4, kof = g * 8;
  int mg = wid & 1, og = wid >> 1;          // M-half, O-group(64)
  const int arow = t >> 3;                  // 0..127 (= b)
  const int aks = (t & 7) * 4;              // f32 k-offset 0..28

  f32x4 acc[4][4];
#pragma unroll
  for (int i = 0; i < 4; ++i)
#pragma unroll
    for (int j = 0; j < 4; ++j) acc[i][j] = (f32x4){0.f, 0.f, 0.f, 0.f};

  const float* abase = enc + ((size_t)l * 128 + arow) * 512 + aks;
  const u16* bbase = Wenc + (size_t)(og * 64 + fr) * 512 + kof;

  float4 pA = *(const float4*)abase;
  bf16x8 cb[4];
#pragma unroll
  for (int ni = 0; ni < 4; ++ni)
    cb[ni] = *(const bf16x8*)(bbase + (size_t)(ni * 16) * 512);

#pragma unroll 2
  for (int step = 0; step < 16; ++step) {
    int sel = step & 1;
    __syncthreads();
    {
      f32x4 fv = {pA.x, pA.y, pA.z, pA.w};
      bf16x4 bv = __builtin_convertvector(fv, bf16x4);
      *(bf16x4*)(&As[sel][arow * 40 + aks]) = bv;
    }
    bf16x8 nb[4];
#pragma unroll
    for (int ni = 0; ni < 4; ++ni) nb[ni] = cb[ni];
    if (step < 15) {
      int kt = (step + 1) * 32;
      pA = *(const float4*)(abase + kt);
#pragma unroll
      for (int ni = 0; ni < 4; ++ni)
        nb[ni] = *(const bf16x8*)(bbase + (size_t)(ni * 16) * 512 + kt);
    }
    __syncthreads();
#pragma unroll
    for (int mi = 0; mi < 4; ++mi) {
      bf16x8 av = *(const bf16x8*)(&As[sel][(mg * 64 + mi * 16 + fr) * 40 + kof]);
#pragma unroll
      for (int ni = 0; ni < 4; ++ni)
        acc[mi][ni] = __builtin_amdgcn_mfma_f32_16x16x32_bf16(av, cb[ni], acc[mi][ni], 0, 0, 0);
    }
#pragma unroll
    for (int ni = 0; ni < 4; ++ni) cb[ni] = nb[ni];
  }
  // epilogue: +qW, tanh, *scW, reduce this wave's 64 o's per row
#pragma unroll
  for (int mi = 0; mi < 4; ++mi) {
    float rs0 = 0.f, rs1 = 0.f, rs2 = 0.f, rs3 = 0.f;
#pragma unroll
    for (int ni = 0; ni < 4; ++ni) {
      int o = og * 64 + ni * 16 + fr;
      float sw = scW[o];
      int brow = mg * 64 + mi * 16 + g * 4;
      rs0 += sw * fast_tanh(acc[mi][ni][0] + qW[(size_t)(brow + 0) * 512 + o]);
      rs1 += sw * fast_tanh(acc[mi][ni][1] + qW[(size_t)(brow + 1) * 512 + o]);
      rs2 += sw * fast_tanh(acc[mi][ni][2] + qW[(size_t)(brow + 2) * 512 + o]);
      rs3 += sw * fast_tanh(acc[mi][ni][3] + qW[(size_t)(brow + 3) * 512 + o]);
    }
#pragma unroll
    for (int d = 1; d < 16; d <<= 1) {
      rs0 += __shfl_xor(rs0, d);
      rs1 += __shfl_xor(rs1, d);
      rs2 += __shfl_xor(rs2, d);
      rs3 += __shfl_xor(rs3, d);
    }
    if (fr < 4) {
      float v = (fr == 0) ? rs0 : (fr == 1) ? rs1 : (fr == 2) ? rs2 : rs3;
      part[wid * 64 + mi * 16 + g * 4 + fr] = v;
    }
  }
  __syncthreads();
  if (t < 128) {
    int mg2 = t >> 6, r64 = t & 63;
    float s = 0.f;
#pragma unroll
    for (int o2 = 0; o2 < 8; ++o2) s += part[(o2 * 2 + mg2) * 64 + r64];
    scores[(size_t)t * 512 + l] = s;
  }
}

// =======================================================================
// mask + softmax + context. grid 2048 = (b, 32-col chunk c in [0,16)).
// scores now complete (single array).
// =======================================================================
__global__ __launch_bounds__(256)
void softctx_kernel(const float* __restrict__ sp, const void* __restrict__ maskp,
                    const int* __restrict__ flag, const float* __restrict__ enc,
                    u16* __restrict__ X0bf, u16* __restrict__ c1bf) {
  __shared__ float wgt[512];
  __shared__ float redm[4], reds[4];
  __shared__ float ps[256 * 2];
  int blk = blockIdx.x, t = threadIdx.x;
  int lane = t & 63, wid = t >> 6;
  int b = blk >> 4, c = blk & 15;
  int l0 = t, l1 = t + 256;
  float s0 = sp[(size_t)b * 512 + l0];
  float s1 = sp[(size_t)b * 512 + l1];
  bool isbyte = (*flag != 0);
  bool m0, m1;
  if (isbyte) {
    m0 = ((const uint8_t*)maskp)[b * 512 + l0] != 0;
    m1 = ((const uint8_t*)maskp)[b * 512 + l1] != 0;
  } else {
    m0 = ((const int*)maskp)[b * 512 + l0] != 0;
    m1 = ((const int*)maskp)[b * 512 + l1] != 0;
  }
  float v0 = m0 ? -1e12f : s0;
  float v1 = m1 ? -1e12f : s1;
  float mx = fmaxf(v0, v1);
#pragma unroll
  for (int d = 1; d < 64; d <<= 1) mx = fmaxf(mx, __shfl_xor(mx, d));
  if (lane == 0) redm[wid] = mx;
  __syncthreads();
  mx = fmaxf(fmaxf(redm[0], redm[1]), fmaxf(redm[2], redm[3]));
  float e0 = __expf(v0 - mx), e1 = __expf(v1 - mx);
  float sm = e0 + e1;
#pragma unroll
  for (int d = 1; d < 64; d <<= 1) sm += __shfl_xor(sm, d);
  if (lane == 0) reds[wid] = sm;
  __syncthreads();
  sm = reds[0] + reds[1] + reds[2] + reds[3];
  float inv = 1.0f / sm;
  wgt[l0] = e0 * inv;
  wgt[l1] = e1 * inv;
  __syncthreads();
  int cp = t & 15, lq = t >> 4;
  int col = c * 32 + cp * 2;
  float a0 = 0.f, a1 = 0.f;
  const float* ebase = enc + (size_t)b * 512 + col;
#pragma unroll 4
  for (int l2 = lq * 32; l2 < lq * 32 + 32; ++l2) {
    float wl = wgt[l2];
    float2 ev = *(const float2*)(ebase + (size_t)l2 * 65536);
    a0 += wl * ev.x;
    a1 += wl * ev.y;
  }
  ps[(lq * 16 + cp) * 2 + 0] = a0;
  ps[(lq * 16 + cp) * 2 + 1] = a1;
  __syncthreads();
  if (t < 16) {
    float r0 = 0.f, r1 = 0.f;
#pragma unroll
    for (int q2 = 0; q2 < 16; ++q2) {
      r0 += ps[(q2 * 16 + t) * 2 + 0];
      r1 += ps[(q2 * 16 + t) * 2 + 1];
    }
    int cc = c * 32 + t * 2;
    uint32_t packed = pk2(r0, r1);
    *(uint32_t*)(X0bf + b * 1536 + 512 + cc) = packed;
    *(uint32_t*)(c1bf + b * 1024 + 512 + cc) = packed;
  }
}

// =======================================================================
// GRU layer: GEMM (gate-interleaved W: row 4o+g) + fused combine epilogue.
// =======================================================================
__global__ __launch_bounds__(256)
void gru_gemm_kernel(const u16* __restrict__ X, int ldx, const u16* __restrict__ Wp,
                     const float* __restrict__ biasp, const float* __restrict__ hprev,
                     int K, float* __restrict__ hout, u16* __restrict__ xdst) {
  __shared__ float ct[128][36];
  int n0 = blockIdx.x * 32;
  int t = threadIdx.x, lane = t & 63, w = t >> 6;
  int fr = lane & 15, g = lane >> 4, kof = g * 8;
  f32x4 acc[2][2];
#pragma unroll
  for (int i = 0; i < 2; ++i)
#pragma unroll
    for (int j = 0; j < 2; ++j) acc[i][j] = (f32x4){0.f, 0.f, 0.f, 0.f};
  const u16* Xr0 = X + (size_t)(w * 32 + fr) * ldx;
  const u16* Xr1 = Xr0 + (size_t)16 * ldx;
  const u16* Wr0 = Wp + (size_t)(n0 + fr) * K;
  const u16* Wr1 = Wp + (size_t)(n0 + 16 + fr) * K;
#pragma unroll 4
  for (int kt = 0; kt < K; kt += 32) {
    bf16x8 a0 = *(const bf16x8*)(Xr0 + kt + kof);
    bf16x8 a1 = *(const bf16x8*)(Xr1 + kt + kof);
    bf16x8 b0 = *(const bf16x8*)(Wr0 + kt + kof);
    bf16x8 b1 = *(const bf16x8*)(Wr1 + kt + kof);
    acc[0][0] = __builtin_amdgcn_mfma_f32_16x16x32_bf16(a0, b0, acc[0][0], 0, 0, 0);
    acc[0][1] = __builtin_amdgcn_mfma_f32_16x16x32_bf16(a0, b1, acc[0][1], 0, 0, 0);
    acc[1][0] = __builtin_amdgcn_mfma_f32_16x16x32_bf16(a1, b0, acc[1][0], 0, 0, 0);
    acc[1][1] = __builtin_amdgcn_mfma_f32_16x16x32_bf16(a1, b1, acc[1][1], 0, 0, 0);
  }
#pragma unroll
  for (int mi = 0; mi < 2; ++mi)
#pragma unroll
    for (int ni = 0; ni < 2; ++ni) {
      int col = ni * 16 + fr;
      float vb = biasp[n0 + col];
#pragma unroll
      for (int j = 0; j < 4; ++j)
        ct[w * 32 + 16 * mi + g * 4 + j][col] = acc[mi][ni][j] + vb;
    }
  __syncthreads();
#pragma unroll
  for (int i = 0; i < 4; ++i) {
    int u = t + i * 256;
    int b = u >> 3, ol = u & 7;
    float cr  = ct[b][ol * 4 + 0];
    float cz  = ct[b][ol * 4 + 1];
    float ci  = ct[b][ol * 4 + 2];
    float chh = ct[b][ol * 4 + 3];
    int o = blockIdx.x * 8 + ol;
    float r = fast_sig(cr), z = fast_sig(cz);
    float n = tanhf(ci + r * chh);
    float h = (1.0f - z) * n + z * hprev[b * 512 + o];
    hout[b * 512 + o] = h;
    xdst[b * 1024 + o] = f2bf(h);
  }
}

// =======================================================================
// thin GEMM, N-tile 32: C = act(X @ W^T + bias). grid N/32, block 256.
// =======================================================================
__global__ __launch_bounds__(256)
void thin_gemm32(const u16* __restrict__ X, int ldx, const u16* __restrict__ W,
                 const float* __restrict__ bias, float* __restrict__ C, int ldc,
                 int K, int act) {
  int n0 = blockIdx.x * 32;
  int t = threadIdx.x, lane = t & 63, w = t >> 6;
  int fr = lane & 15, g = lane >> 4, kof = g * 8;
  f32x4 acc[2][2];
#pragma unroll
  for (int i = 0; i < 2; ++i)
#pragma unroll
    for (int j = 0; j < 2; ++j) acc[i][j] = (f32x4){0.f, 0.f, 0.f, 0.f};
  const u16* Xr0 = X + (size_t)(w * 32 + fr) * ldx;
  const u16* Xr1 = Xr0 + (size_t)16 * ldx;
  const u16* Wr0 = W + (size_t)(n0 + fr) * K;
  const u16* Wr1 = W + (size_t)(n0 + 16 + fr) * K;
#pragma unroll 4
  for (int kt = 0; kt < K; kt += 32) {
    bf16x8 a0 = *(const bf16x8*)(Xr0 + kt + kof);
    bf16x8 a1 = *(const bf16x8*)(Xr1 + kt + kof);
    bf16x8 b0 = *(const bf16x8*)(Wr0 + kt + kof);
    bf16x8 b1 = *(const bf16x8*)(Wr1 + kt + kof);
    acc[0][0] = __builtin_amdgcn_mfma_f32_16x16x32_bf16(a0, b0, acc[0][0], 0, 0, 0);
    acc[0][1] = __builtin_amdgcn_mfma_f32_16x16x32_bf16(a0, b1, acc[0][1], 0, 0, 0);
    acc[1][0] = __builtin_amdgcn_mfma_f32_16x16x32_bf16(a1, b0, acc[1][0], 0, 0, 0);
    acc[1][1] = __builtin_amdgcn_mfma_f32_16x16x32_bf16(a1, b1, acc[1][1], 0, 0, 0);
  }
#pragma unroll
  for (int mi = 0; mi < 2; ++mi)
#pragma unroll
    for (int ni = 0; ni < 2; ++ni) {
      int col = n0 + ni * 16 + fr;
      float vb = bias[col];
#pragma unroll
      for (int j = 0; j < 4; ++j) {
        int row = w * 32 + 16 * mi + g * 4 + j;
        float v = acc[mi][ni][j] + vb;
        if (act) v = tanhf(v);
        C[(size_t)row * ldc + col] = v;
      }
    }
}

extern "C" void kernel_launch(void* const* d_in, const int* in_sizes, int n_in,
                              void* d_out, int out_size, void* d_ws, size_t ws_size,
                              hipStream_t stream) {
  const int*   ids    = (const int*)  d_in[0];
  const float* lh     = (const float*)d_in[1];
  const float* wdv    = (const float*)d_in[2];
  const float* enc    = (const float*)d_in[3];
  const void*  mask   = d_in[4];
  const float* attn_W = (const float*)d_in[5];
  const float* attn_b = (const float*)d_in[6];
  const float* scW    = (const float*)d_in[7];
  const float* cat_W  = (const float*)d_in[8];
  const float* cat_b  = (const float*)d_in[9];
  const float* W_ih0  = (const float*)d_in[10];
  const float* W_hh0  = (const float*)d_in[11];
  const float* b_ih0  = (const float*)d_in[12];
  const float* b_hh0  = (const float*)d_in[13];
  const float* W_ih1  = (const float*)d_in[14];
  const float* W_hh1  = (const float*)d_in[15];
  const float* b_ih1  = (const float*)d_in[16];
  const float* b_hh1  = (const float*)d_in[17];

  float* out = (float*)d_out;
  float* h0  = out + 65536;
  float* h1  = out + 131072;

  float* ws     = (float*)d_ws;
  float* qW     = ws;                      // 65536
  float* scores = ws + 65536;              // 65536
  float* biasg0 = ws + 131072;             // 2048
  float* biasg1 = ws + 133120;             // 2048
  int*   flag   = (int*)(ws + 135168);     // 16
  u16*   arena  = (u16*)(ws + 135184);     // 6029312 u16
  u16*   X0bf   = (u16*)(ws + 3149840);    // 196608 u16
  u16*   X1bf   = (u16*)(ws + 3248144);    // 131072 u16
  u16*   c1bf   = (u16*)(ws + 3313680);    // 131072 u16

  const u16* Wenc = arena;
  const u16* Wcat = arena + 262144;
  const u16* Wg0p = arena + 786432;
  const u16* Wg1p = arena + 3932160;

  prep_kernel<<<3059, 512, 0, stream>>>(lh, attn_W, attn_b, cat_W,
                                        W_ih0, W_hh0, W_ih1, W_hh1,
                                        b_ih0, b_hh0, b_ih1, b_hh1,
                                        wdv, ids, mask,
                                        qW, arena, biasg0, biasg1, X0bf, X1bf, flag);
  attn_kernel<<<512, 1024, 0, stream>>>(enc, Wenc, qW, scW, scores);
  softctx_kernel<<<2048, 256, 0, stream>>>(scores, mask, flag, enc, X0bf, c1bf);
  gru_gemm_kernel<<<64, 256, 0, stream>>>(X0bf, 1536, Wg0p, biasg0, lh, 1536, h0, X1bf);
  gru_gemm_kernel<<<64, 256, 0, stream>>>(X1bf, 1024, Wg1p, biasg1, lh + 65536, 1024, h1, c1bf);
  thin_gemm32<<<16, 256, 0, stream>>>(c1bf, 1024, Wcat, cat_b, out, 512, 1024, 1);
}

// Round 17
// 172.614 us; speedup vs baseline: 1.1479x; 1.1360x over previous
//
#include <hip/hip_runtime.h>
#include <stdint.h>

#define Hdim 512
#define Bdim 128
#define Ldim 512
#define Vdim 2048

typedef unsigned short u16;
using f32x4  = float  __attribute__((ext_vector_type(4)));
using f32x8  = float  __attribute__((ext_vector_type(8)));
using bf16x8 = __bf16 __attribute__((ext_vector_type(8)));
using bf16x2 = __bf16 __attribute__((ext_vector_type(2)));

// Native casts -> compiler emits v_cvt_pk_bf16_f32 (RNE).
__device__ inline u16 f2bf(float x) {
  __bf16 b = (__bf16)x;
  union { __bf16 b; u16 u; } c; c.b = b; return c.u;
}
__device__ inline uint32_t pk2(float lo, float hi) {
  union { bf16x2 v; uint32_t u; } c;
  c.v[0] = (__bf16)lo; c.v[1] = (__bf16)hi;
  return c.u;
}
__device__ inline float fast_tanh(float x) {
  return 1.0f - 2.0f / (__expf(2.0f * x) + 1.0f);
}
__device__ inline float fast_sig(float x) { return 1.0f / (1.0f + __expf(-x)); }

__device__ inline bf16x8 pack_bf8(float4 x, float4 y) {
  f32x8 f = {x.x, x.y, x.z, x.w, y.x, y.y, y.z, y.w};
  return __builtin_convertvector(f, bf16x8);
}

// =======================================================================
// prep: blk<16 -> qW GEMM (f32 direct, in-reg cvt); blk==16 -> mask detect;
// blk>=17 -> bf16 weight arena + fused biases + emb gather + lh copies.
// arena: Wenc@0 (512x512), Wcat@262144 (512x1024), Wg0p@786432 (2048x1536),
//        Wg1p@3932160 (2048x1024)  total 6029312 u16
// =======================================================================
__global__ __launch_bounds__(512)
void prep_kernel(const float* __restrict__ lh, const float* __restrict__ attn_W,
                 const float* __restrict__ attn_b, const float* __restrict__ cat_W,
                 const float* __restrict__ W_ih0, const float* __restrict__ W_hh0,
                 const float* __restrict__ W_ih1, const float* __restrict__ W_hh1,
                 const float* __restrict__ b_ih0, const float* __restrict__ b_hh0,
                 const float* __restrict__ b_ih1, const float* __restrict__ b_hh1,
                 const float* __restrict__ wdv, const int* __restrict__ ids,
                 const void* __restrict__ mask,
                 float* __restrict__ qW, u16* __restrict__ arena,
                 float* __restrict__ biasg0, float* __restrict__ biasg1,
                 u16* __restrict__ X0bf, u16* __restrict__ X1bf, int* __restrict__ flag) {
  int blk = blockIdx.x, t = threadIdx.x;
  int lane = t & 63, wid = t >> 6;
  int fr = lane & 15, g = lane >> 4, kof = g * 8;

  if (blk < 16) {
    // qW = q @ attn_W[:, :512]^T + attn_b
    int mh = wid & 3, nh = wid >> 2;
    int n0 = blk * 32 + nh * 16;
    int rb0 = mh * 32;
    f32x4 ac0 = {0.f, 0.f, 0.f, 0.f}, ac1 = {0.f, 0.f, 0.f, 0.f};
    const float* q = lh + 65536;
#pragma unroll 2
    for (int kt = 0; kt < 512; kt += 32) {
      const float* qr0 = q + (size_t)(rb0 + fr) * 512 + kt + kof;
      const float* qr1 = qr0 + 16 * 512;
      const float* wr  = attn_W + (size_t)(n0 + fr) * 1024 + kt + kof;
      float4 x0 = *(const float4*)qr0, x1 = *(const float4*)(qr0 + 4);
      float4 y0 = *(const float4*)qr1, y1 = *(const float4*)(qr1 + 4);
      float4 w0 = *(const float4*)wr,  w1 = *(const float4*)(wr + 4);
      bf16x8 A0 = pack_bf8(x0, x1), A1 = pack_bf8(y0, y1), Bb = pack_bf8(w0, w1);
      ac0 = __builtin_amdgcn_mfma_f32_16x16x32_bf16(A0, Bb, ac0, 0, 0, 0);
      ac1 = __builtin_amdgcn_mfma_f32_16x16x32_bf16(A1, Bb, ac1, 0, 0, 0);
    }
    float vb = attn_b[n0 + fr];
#pragma unroll
    for (int j = 0; j < 4; ++j) {
      qW[(size_t)(rb0 + g * 4 + j) * 512 + n0 + fr]      = ac0[j] + vb;
      qW[(size_t)(rb0 + 16 + g * 4 + j) * 512 + n0 + fr] = ac1[j] + vb;
    }
    return;
  }
  if (blk == 16) {                              // mask dtype detect
    __shared__ int sf;
    if (t == 0) sf = 0;
    __syncthreads();
    const uint32_t* m32 = (const uint32_t*)mask;
    int found = 0;
    for (int i = t; i < 16384; i += 512)
      if (m32[i] & 0xffffff00u) found = 1;      // nonzero byte at pos%4!=0 => byte mask
    if (found) sf = 1;
    __syncthreads();
    if (t == 0) *flag = sf;
    return;
  }
  // arena + biases + gather, one quad per thread
  const int ARENA_Q = 1507328;
  int i = (blk - 17) * 512 + t;
  if (i < ARENA_Q) {
    int e = i * 4;
    float4 v = {0.f, 0.f, 0.f, 0.f};
    if (e < 262144) {                           // Wenc = attn_W[:, 512:]
      int o = e >> 9, k = e & 511;
      v = *(const float4*)(attn_W + (size_t)o * 1024 + 512 + k);
    } else if (e < 786432) {                    // Wcat
      int e2 = e - 262144; int o = e2 >> 10, k = e2 & 1023;
      v = *(const float4*)(cat_W + (size_t)o * 1024 + k);
    } else if (e < 3932160) {                   // Wg0p [2048=4o+g][1536]
      int e2 = e - 786432; int row = e2 / 1536, k = e2 % 1536;
      int o = row >> 2, gt = row & 3;
      if (gt == 0)      v = (k < 1024) ? *(const float4*)(W_ih0 + (size_t)o * 1024 + k)
                                       : *(const float4*)(W_hh0 + (size_t)o * 512 + k - 1024);
      else if (gt == 1) v = (k < 1024) ? *(const float4*)(W_ih0 + (size_t)(512 + o) * 1024 + k)
                                       : *(const float4*)(W_hh0 + (size_t)(512 + o) * 512 + k - 1024);
      else if (gt == 2) { if (k < 1024)  v = *(const float4*)(W_ih0 + (size_t)(1024 + o) * 1024 + k); }
      else              { if (k >= 1024) v = *(const float4*)(W_hh0 + (size_t)(1024 + o) * 512 + k - 1024); }
    } else {                                    // Wg1p [2048=4o+g][1024]
      int e2 = e - 3932160; int row = e2 >> 10, k = e2 & 1023;
      int o = row >> 2, gt = row & 3;
      if (gt == 0)      v = (k < 512) ? *(const float4*)(W_ih1 + (size_t)o * 512 + k)
                                      : *(const float4*)(W_hh1 + (size_t)o * 512 + k - 512);
      else if (gt == 1) v = (k < 512) ? *(const float4*)(W_ih1 + (size_t)(512 + o) * 512 + k)
                                      : *(const float4*)(W_hh1 + (size_t)(512 + o) * 512 + k - 512);
      else if (gt == 2) { if (k < 512)  v = *(const float4*)(W_ih1 + (size_t)(1024 + o) * 512 + k); }
      else              { if (k >= 512) v = *(const float4*)(W_hh1 + (size_t)(1024 + o) * 512 + k - 512); }
    }
    ushort4 u;
    u.x = f2bf(v.x); u.y = f2bf(v.y); u.z = f2bf(v.z); u.w = f2bf(v.w);
    *(ushort4*)(arena + e) = u;
    return;
  }
  int i2 = i - ARENA_Q;
  if (i2 < 1024) {                              // biases, 4o+g quads
    int r4 = i2 * 4; int layer = r4 >> 11; int r = r4 & 2047; int o = r >> 2;
    const float* bi = layer ? b_ih1 : b_ih0;
    const float* bh = layer ? b_hh1 : b_hh0;
    float4 v;
    v.x = bi[o] + bh[o];
    v.y = bi[512 + o] + bh[512 + o];
    v.z = bi[1024 + o];
    v.w = bh[1024 + o];
    *(float4*)((layer ? biasg1 : biasg0) + r) = v;
  } else if (i2 < 1024 + 16384) {               // emb gather
    int j = (i2 - 1024) * 4; int b = j >> 9, i0 = j & 511;
    float4 v = *(const float4*)(wdv + (size_t)b * (Vdim * Hdim) + (size_t)ids[b] * 512 + i0);
    ushort4 u;
    u.x = f2bf(v.x); u.y = f2bf(v.y); u.z = f2bf(v.z); u.w = f2bf(v.w);
    *(ushort4*)(X0bf + b * 1536 + i0) = u;
  } else if (i2 < 1024 + 32768) {               // lh0 -> X0bf[:,1024:]
    int j = (i2 - 1024 - 16384) * 4; int b = j >> 9, i0 = j & 511;
    float4 v = *(const float4*)(lh + (size_t)b * 512 + i0);
    ushort4 u;
    u.x = f2bf(v.x); u.y = f2bf(v.y); u.z = f2bf(v.z); u.w = f2bf(v.w);
    *(ushort4*)(X0bf + b * 1536 + 1024 + i0) = u;
  } else if (i2 < 1024 + 49152) {               // q -> X1bf[:,512:]
    int j = (i2 - 1024 - 32768) * 4; int b = j >> 9, i0 = j & 511;
    float4 v = *(const float4*)(lh + 65536 + (size_t)b * 512 + i0);
    ushort4 u;
    u.x = f2bf(v.x); u.y = f2bf(v.y); u.z = f2bf(v.z); u.w = f2bf(v.w);
    *(ushort4*)(X1bf + b * 1024 + 512 + i0) = u;
  }
}

// =======================================================================
// attention energies (R10 tiling + depth-2 A prefetch + cvt_pk staging).
// grid 1024: one (l, oh) 128x256 tile per block.
// =======================================================================
__global__ __launch_bounds__(512)
void attn_kernel(const float* __restrict__ enc, const u16* __restrict__ Wenc,
                 const float* __restrict__ qW, const float* __restrict__ scW,
                 float* __restrict__ scores_p) {
  __shared__ __align__(16) u16 As[2][128 * 40];
  __shared__ float part[8 * 128];
  int blk = blockIdx.x, t = threadIdx.x;
  int lane = t & 63, wid = t >> 6;
  int fr = lane & 15, g = lane >> 4, kof = g * 8;
  int l  = (blk >> 4) * 8 + (blk & 7);
  int oh = (blk >> 3) & 1;
  int ob = oh * 256;
  const int arow = t >> 2;             // 0..127
  const int aks = (t & 3) * 8;

  f32x4 acc[8][2];
#pragma unroll
  for (int i = 0; i < 8; ++i) {
    acc[i][0] = (f32x4){0.f, 0.f, 0.f, 0.f};
    acc[i][1] = (f32x4){0.f, 0.f, 0.f, 0.f};
  }
  const float* abase = enc + ((size_t)l * 128 + arow) * 512 + aks;
  const u16* bptr0 = Wenc + (size_t)(ob + wid * 32 + fr) * 512 + kof;
  const u16* bptr1 = bptr0 + (size_t)16 * 512;

  // depth-2 A prefetch: pA = data for next stage, pB = one step beyond
  float4 pA0 = *(const float4*)abase;
  float4 pA1 = *(const float4*)(abase + 4);
  float4 pB0 = *(const float4*)(abase + 32);
  float4 pB1 = *(const float4*)(abase + 36);
  bf16x8 cb0 = *(const bf16x8*)bptr0;
  bf16x8 cb1 = *(const bf16x8*)bptr1;

#pragma unroll 2
  for (int step = 0; step < 16; ++step) {
    int sel = step & 1;
    __syncthreads();
    bf16x8 apv = pack_bf8(pA0, pA1);           // v_cvt_pk_bf16_f32 x4
    *(bf16x8*)(&As[sel][arow * 40 + aks]) = apv;
    // rotate A pipeline; issue load for step+2
    pA0 = pB0; pA1 = pB1;
    if (step < 14) {
      int kt = (step + 2) * 32;
      pB0 = *(const float4*)(abase + kt);
      pB1 = *(const float4*)(abase + kt + 4);
    }
    // B prefetch for step+1
    bf16x8 nb0 = cb0, nb1 = cb1;
    if (step < 15) {
      int kt = (step + 1) * 32;
      nb0 = *(const bf16x8*)(bptr0 + kt);
      nb1 = *(const bf16x8*)(bptr1 + kt);
    }
    __syncthreads();
#pragma unroll
    for (int mi = 0; mi < 8; ++mi) {
      bf16x8 av = *(const bf16x8*)(&As[sel][(mi * 16 + fr) * 40 + kof]);
      acc[mi][0] = __builtin_amdgcn_mfma_f32_16x16x32_bf16(av, cb0, acc[mi][0], 0, 0, 0);
      acc[mi][1] = __builtin_amdgcn_mfma_f32_16x16x32_bf16(av, cb1, acc[mi][1], 0, 0, 0);
    }
    cb0 = nb0; cb1 = nb1;
  }
  // epilogue: +qW, tanh, *scW, reduce over this block's 256 o's
#pragma unroll
  for (int mi = 0; mi < 8; ++mi) {
    float rs0 = 0.f, rs1 = 0.f, rs2 = 0.f, rs3 = 0.f;
#pragma unroll
    for (int ni = 0; ni < 2; ++ni) {
      int o = ob + wid * 32 + ni * 16 + fr;
      float sw = scW[o];
      int brow = mi * 16 + g * 4;
      rs0 += sw * fast_tanh(acc[mi][ni][0] + qW[(size_t)(brow + 0) * 512 + o]);
      rs1 += sw * fast_tanh(acc[mi][ni][1] + qW[(size_t)(brow + 1) * 512 + o]);
      rs2 += sw * fast_tanh(acc[mi][ni][2] + qW[(size_t)(brow + 2) * 512 + o]);
      rs3 += sw * fast_tanh(acc[mi][ni][3] + qW[(size_t)(brow + 3) * 512 + o]);
    }
#pragma unroll
    for (int d = 1; d < 16; d <<= 1) {
      rs0 += __shfl_xor(rs0, d);
      rs1 += __shfl_xor(rs1, d);
      rs2 += __shfl_xor(rs2, d);
      rs3 += __shfl_xor(rs3, d);
    }
    if (fr < 4) {
      float v = (fr == 0) ? rs0 : (fr == 1) ? rs1 : (fr == 2) ? rs2 : rs3;
      part[wid * 128 + mi * 16 + g * 4 + fr] = v;
    }
  }
  __syncthreads();
  if (t < 128) {
    float s = 0.f;
#pragma unroll
    for (int w2 = 0; w2 < 8; ++w2) s += part[w2 * 128 + t];
    scores_p[(size_t)(oh * 128 + t) * 512 + l] = s;
  }
}

// =======================================================================
// mask + softmax + context. grid 2048 = (b, 32-col chunk c in [0,16)).
// =======================================================================
__global__ __launch_bounds__(256)
void softctx_kernel(const float* __restrict__ sp, const void* __restrict__ maskp,
                    const int* __restrict__ flag, const float* __restrict__ enc,
                    u16* __restrict__ X0bf, u16* __restrict__ c1bf) {
  __shared__ float wgt[512];
  __shared__ float redm[4], reds[4];
  __shared__ float ps[256 * 2];
  int blk = blockIdx.x, t = threadIdx.x;
  int lane = t & 63, wid = t >> 6;
  int b = blk >> 4, c = blk & 15;
  int l0 = t, l1 = t + 256;
  float s0 = sp[(size_t)b * 512 + l0] + sp[(size_t)(128 + b) * 512 + l0];
  float s1 = sp[(size_t)b * 512 + l1] + sp[(size_t)(128 + b) * 512 + l1];
  bool isbyte = (*flag != 0);
  bool m0, m1;
  if (isbyte) {
    m0 = ((const uint8_t*)maskp)[b * 512 + l0] != 0;
    m1 = ((const uint8_t*)maskp)[b * 512 + l1] != 0;
  } else {
    m0 = ((const int*)maskp)[b * 512 + l0] != 0;
    m1 = ((const int*)maskp)[b * 512 + l1] != 0;
  }
  float v0 = m0 ? -1e12f : s0;
  float v1 = m1 ? -1e12f : s1;
  float mx = fmaxf(v0, v1);
#pragma unroll
  for (int d = 1; d < 64; d <<= 1) mx = fmaxf(mx, __shfl_xor(mx, d));
  if (lane == 0) redm[wid] = mx;
  __syncthreads();
  mx = fmaxf(fmaxf(redm[0], redm[1]), fmaxf(redm[2], redm[3]));
  float e0 = __expf(v0 - mx), e1 = __expf(v1 - mx);
  float sm = e0 + e1;
#pragma unroll
  for (int d = 1; d < 64; d <<= 1) sm += __shfl_xor(sm, d);
  if (lane == 0) reds[wid] = sm;
  __syncthreads();
  sm = reds[0] + reds[1] + reds[2] + reds[3];
  float inv = 1.0f / sm;
  wgt[l0] = e0 * inv;
  wgt[l1] = e1 * inv;
  __syncthreads();
  int cp = t & 15, lq = t >> 4;
  int col = c * 32 + cp * 2;
  float a0 = 0.f, a1 = 0.f;
  const float* ebase = enc + (size_t)b * 512 + col;
#pragma unroll 4
  for (int l2 = lq * 32; l2 < lq * 32 + 32; ++l2) {
    float wl = wgt[l2];
    float2 ev = *(const float2*)(ebase + (size_t)l2 * 65536);
    a0 += wl * ev.x;
    a1 += wl * ev.y;
  }
  ps[(lq * 16 + cp) * 2 + 0] = a0;
  ps[(lq * 16 + cp) * 2 + 1] = a1;
  __syncthreads();
  if (t < 16) {
    float r0 = 0.f, r1 = 0.f;
#pragma unroll
    for (int q2 = 0; q2 < 16; ++q2) {
      r0 += ps[(q2 * 16 + t) * 2 + 0];
      r1 += ps[(q2 * 16 + t) * 2 + 1];
    }
    int cc = c * 32 + t * 2;
    uint32_t packed = pk2(r0, r1);
    *(uint32_t*)(X0bf + b * 1536 + 512 + cc) = packed;
    *(uint32_t*)(c1bf + b * 1024 + 512 + cc) = packed;
  }
}

// =======================================================================
// GRU layer: GEMM (gate-interleaved W: row 4o+g) + fused combine epilogue.
// =======================================================================
__global__ __launch_bounds__(256)
void gru_gemm_kernel(const u16* __restrict__ X, int ldx, const u16* __restrict__ Wp,
                     const float* __restrict__ biasp, const float* __restrict__ hprev,
                     int K, float* __restrict__ hout, u16* __restrict__ xdst) {
  __shared__ float ct[128][36];
  int n0 = blockIdx.x * 32;
  int t = threadIdx.x, lane = t & 63, w = t >> 6;
  int fr = lane & 15, g = lane >> 4, kof = g * 8;
  f32x4 acc[2][2];
#pragma unroll
  for (int i = 0; i < 2; ++i)
#pragma unroll
    for (int j = 0; j < 2; ++j) acc[i][j] = (f32x4){0.f, 0.f, 0.f, 0.f};
  const u16* Xr0 = X + (size_t)(w * 32 + fr) * ldx;
  const u16* Xr1 = Xr0 + (size_t)16 * ldx;
  const u16* Wr0 = Wp + (size_t)(n0 + fr) * K;
  const u16* Wr1 = Wp + (size_t)(n0 + 16 + fr) * K;
#pragma unroll 4
  for (int kt = 0; kt < K; kt += 32) {
    bf16x8 a0 = *(const bf16x8*)(Xr0 + kt + kof);
    bf16x8 a1 = *(const bf16x8*)(Xr1 + kt + kof);
    bf16x8 b0 = *(const bf16x8*)(Wr0 + kt + kof);
    bf16x8 b1 = *(const bf16x8*)(Wr1 + kt + kof);
    acc[0][0] = __builtin_amdgcn_mfma_f32_16x16x32_bf16(a0, b0, acc[0][0], 0, 0, 0);
    acc[0][1] = __builtin_amdgcn_mfma_f32_16x16x32_bf16(a0, b1, acc[0][1], 0, 0, 0);
    acc[1][0] = __builtin_amdgcn_mfma_f32_16x16x32_bf16(a1, b0, acc[1][0], 0, 0, 0);
    acc[1][1] = __builtin_amdgcn_mfma_f32_16x16x32_bf16(a1, b1, acc[1][1], 0, 0, 0);
  }
#pragma unroll
  for (int mi = 0; mi < 2; ++mi)
#pragma unroll
    for (int ni = 0; ni < 2; ++ni) {
      int col = ni * 16 + fr;
      float vb = biasp[n0 + col];
#pragma unroll
      for (int j = 0; j < 4; ++j)
        ct[w * 32 + 16 * mi + g * 4 + j][col] = acc[mi][ni][j] + vb;
    }
  __syncthreads();
#pragma unroll
  for (int i = 0; i < 4; ++i) {
    int u = t + i * 256;
    int b = u >> 3, ol = u & 7;
    float cr  = ct[b][ol * 4 + 0];
    float cz  = ct[b][ol * 4 + 1];
    float ci  = ct[b][ol * 4 + 2];
    float chh = ct[b][ol * 4 + 3];
    int o = blockIdx.x * 8 + ol;
    float r = fast_sig(cr), z = fast_sig(cz);
    float n = tanhf(ci + r * chh);
    float h = (1.0f - z) * n + z * hprev[b * 512 + o];
    hout[b * 512 + o] = h;
    xdst[b * 1024 + o] = f2bf(h);
  }
}

// =======================================================================
// thin GEMM, N-tile 32: C = act(X @ W^T + bias). grid N/32, block 256.
// =======================================================================
__global__ __launch_bounds__(256)
void thin_gemm32(const u16* __restrict__ X, int ldx, const u16* __restrict__ W,
                 const float* __restrict__ bias, float* __restrict__ C, int ldc,
                 int K, int act) {
  int n0 = blockIdx.x * 32;
  int t = threadIdx.x, lane = t & 63, w = t >> 6;
  int fr = lane & 15, g = lane >> 4, kof = g * 8;
  f32x4 acc[2][2];
#pragma unroll
  for (int i = 0; i < 2; ++i)
#pragma unroll
    for (int j = 0; j < 2; ++j) acc[i][j] = (f32x4){0.f, 0.f, 0.f, 0.f};
  const u16* Xr0 = X + (size_t)(w * 32 + fr) * ldx;
  const u16* Xr1 = Xr0 + (size_t)16 * ldx;
  const u16* Wr0 = W + (size_t)(n0 + fr) * K;
  const u16* Wr1 = W + (size_t)(n0 + 16 + fr) * K;
#pragma unroll 4
  for (int kt = 0; kt < K; kt += 32) {
    bf16x8 a0 = *(const bf16x8*)(Xr0 + kt + kof);
    bf16x8 a1 = *(const bf16x8*)(Xr1 + kt + kof);
    bf16x8 b0 = *(const bf16x8*)(Wr0 + kt + kof);
    bf16x8 b1 = *(const bf16x8*)(Wr1 + kt + kof);
    acc[0][0] = __builtin_amdgcn_mfma_f32_16x16x32_bf16(a0, b0, acc[0][0], 0, 0, 0);
    acc[0][1] = __builtin_amdgcn_mfma_f32_16x16x32_bf16(a0, b1, acc[0][1], 0, 0, 0);
    acc[1][0] = __builtin_amdgcn_mfma_f32_16x16x32_bf16(a1, b0, acc[1][0], 0, 0, 0);
    acc[1][1] = __builtin_amdgcn_mfma_f32_16x16x32_bf16(a1, b1, acc[1][1], 0, 0, 0);
  }
#pragma unroll
  for (int mi = 0; mi < 2; ++mi)
#pragma unroll
    for (int ni = 0; ni < 2; ++ni) {
      int col = n0 + ni * 16 + fr;
      float vb = bias[col];
#pragma unroll
      for (int j = 0; j < 4; ++j) {
        int row = w * 32 + 16 * mi + g * 4 + j;
        float v = acc[mi][ni][j] + vb;
        if (act) v = tanhf(v);
        C[(size_t)row * ldc + col] = v;
      }
    }
}

extern "C" void kernel_launch(void* const* d_in, const int* in_sizes, int n_in,
                              void* d_out, int out_size, void* d_ws, size_t ws_size,
                              hipStream_t stream) {
  const int*   ids    = (const int*)  d_in[0];
  const float* lh     = (const float*)d_in[1];
  const float* wdv    = (const float*)d_in[2];
  const float* enc    = (const float*)d_in[3];
  const void*  mask   = d_in[4];
  const float* attn_W = (const float*)d_in[5];
  const float* attn_b = (const float*)d_in[6];
  const float* scW    = (const float*)d_in[7];
  const float* cat_W  = (const float*)d_in[8];
  const float* cat_b  = (const float*)d_in[9];
  const float* W_ih0  = (const float*)d_in[10];
  const float* W_hh0  = (const float*)d_in[11];
  const float* b_ih0  = (const float*)d_in[12];
  const float* b_hh0  = (const float*)d_in[13];
  const float* W_ih1  = (const float*)d_in[14];
  const float* W_hh1  = (const float*)d_in[15];
  const float* b_ih1  = (const float*)d_in[16];
  const float* b_hh1  = (const float*)d_in[17];

  float* out = (float*)d_out;
  float* h0  = out + 65536;
  float* h1  = out + 131072;

  float* ws       = (float*)d_ws;
  float* qW       = ws;                      // 65536
  float* scores_p = ws + 65536;              // 131072 [2][128][512]
  float* biasg0   = ws + 196608;             // 2048
  float* biasg1   = ws + 198656;             // 2048
  int*   flag     = (int*)(ws + 200704);     // 16
  u16*   arena    = (u16*)(ws + 200720);     // 6029312 u16
  u16*   X0bf     = (u16*)(ws + 3215376);    // 196608 u16
  u16*   X1bf     = (u16*)(ws + 3313680);    // 131072 u16
  u16*   c1bf     = (u16*)(ws + 3379216);    // 131072 u16

  const u16* Wenc = arena;
  const u16* Wcat = arena + 262144;
  const u16* Wg0p = arena + 786432;
  const u16* Wg1p = arena + 3932160;

  prep_kernel<<<3059, 512, 0, stream>>>(lh, attn_W, attn_b, cat_W,
                                        W_ih0, W_hh0, W_ih1, W_hh1,
                                        b_ih0, b_hh0, b_ih1, b_hh1,
                                        wdv, ids, mask,
                                        qW, arena, biasg0, biasg1, X0bf, X1bf, flag);
  attn_kernel<<<1024, 512, 0, stream>>>(enc, Wenc, qW, scW, scores_p);
  softctx_kernel<<<2048, 256, 0, stream>>>(scores_p, mask, flag, enc, X0bf, c1bf);
  gru_gemm_kernel<<<64, 256, 0, stream>>>(X0bf, 1536, Wg0p, biasg0, lh, 1536, h0, X1bf);
  gru_gemm_kernel<<<64, 256, 0, stream>>>(X1bf, 1024, Wg1p, biasg1, lh + 65536, 1024, h1, c1bf);
  thin_gemm32<<<16, 256, 0, stream>>>(c1bf, 1024, Wcat, cat_b, out, 512, 1024, 1);
}